// Round 7
// baseline (262.230 us; speedup 1.0000x reference)
//
#include <hip/hip_runtime.h>
#include <hip/hip_bf16.h>

// GCNConv: out[i] = sum_{e: row[e]=i} dis[row]*dis[col]*xl[col] + dis[i]^2*xl[i]
// N=50000, E=1.6M, D=128, fp32 in/out.
//
// R6 -> R7: k_bin stuck at 78us despite occupancy fix -> theory: bound by its
// random 4B traffic (scattered ebuf stores w/ 21B runs -> 61MB writeback amp,
// + 1.6M random cntc atomics). Changes:
//  - degree atomics moved k_bin -> k_sort (which touches every edge anyway);
//    tiny k_dis after.
//  - RPB 64->256 (NB=196, pack col:16|rl:8|bk:8), TILE 4096->8192:
//    scatter runs 5.2 -> 42 elems (21B -> 168B), write amp ~1x.

#define D     128
#define TILE  8192
#define BINB  1024      // k_bin block size
#define RPB   256       // rows per bucket
#define MAXB  256       // bucket id must fit 8 bits

static __device__ __forceinline__ unsigned short f2bf(float f) {
    unsigned u = __float_as_uint(f);
    u = (u + 0x7FFFu + ((u >> 16) & 1u)) >> 16;   // RNE
    return (unsigned short)u;
}
static __device__ __forceinline__ float bf2f(unsigned short s) {
    return __uint_as_float(((unsigned)s) << 16);
}

// --- init: cntc = 0, bcur[b] = b*CAP -------------------------------------
__global__ __launch_bounds__(256) void k_init(int* __restrict__ cntc,
                                              int* __restrict__ bcur,
                                              int N, int NB, int CAP) {
    int i = blockIdx.x * 256 + threadIdx.x;
    if (i < N) cntc[i] = 0;
    if (i < NB) bcur[i] = i * CAP;
}

// --- single-pass bin into fixed-stride bucket regions --------------------
__global__ __launch_bounds__(BINB) void k_bin(const int* __restrict__ rows,
                                              const int* __restrict__ cols,
                                              int* __restrict__ bcur,
                                              unsigned* __restrict__ ebuf,
                                              int E, int NB, int CAP) {
    __shared__ int lcnt[MAXB];
    __shared__ int lbase[MAXB];
    const int t = threadIdx.x;
    const int base = blockIdx.x * TILE;
    int m = E - base; if (m > TILE) m = TILE;

    unsigned p[TILE / BINB];
    #pragma unroll
    for (int it = 0; it < TILE / BINB; ++it) {
        int i = it * BINB + t;
        if (i < m) {
            unsigned r = (unsigned)rows[base + i];
            unsigned c = (unsigned)cols[base + i];
            p[it] = c | ((r & 255u) << 16) | ((r >> 8) << 24);
        }
    }
    for (int b = t; b < NB; b += BINB) lcnt[b] = 0;
    __syncthreads();
    #pragma unroll
    for (int it = 0; it < TILE / BINB; ++it) {
        int i = it * BINB + t;
        if (i < m) atomicAdd(&lcnt[p[it] >> 24], 1);
    }
    __syncthreads();
    for (int b = t; b < NB; b += BINB) {
        int c = lcnt[b];
        lbase[b] = c ? atomicAdd(&bcur[b], c) : 0;
        lcnt[b] = 0;
    }
    __syncthreads();
    #pragma unroll
    for (int it = 0; it < TILE / BINB; ++it) {
        int i = it * BINB + t;
        if (i < m) {
            int bk = p[it] >> 24;
            int r  = atomicAdd(&lcnt[bk], 1);
            int pos = lbase[bk] + r;
            if (pos < (bk + 1) * CAP)               // overflow guard (never fires)
                ebuf[pos] = p[it] & 0xFFFFFFu;      // col | rowlocal<<16
        }
    }
}

// --- dis = rsqrt(deg_col + 1) --------------------------------------------
__global__ __launch_bounds__(256) void k_dis(const int* __restrict__ cntc,
                                             float* __restrict__ dis, int N) {
    int i = blockIdx.x * 256 + threadIdx.x;
    if (i < N) dis[i] = rsqrtf((float)(cntc[i] + 1));
}

// --- per-bucket counting sort + degree atomics + per-node beg/end --------
__global__ __launch_bounds__(1024) void k_sort(const int* __restrict__ bcur,
                                               const unsigned* __restrict__ ebuf,
                                               int* __restrict__ cntc,
                                               unsigned short* __restrict__ ecol,
                                               int* __restrict__ begN,
                                               int* __restrict__ endN,
                                               int N, int CAP) {
    __shared__ int cnt[RPB];
    __shared__ int excl[RPB];
    const int b = blockIdx.x, t = threadIdx.x;
    const int base = b * CAP;
    int m = bcur[b] - base; if (m > CAP) m = CAP;
    if (t < RPB) cnt[t] = 0;
    __syncthreads();
    for (int i = t; i < m; i += 1024) {
        unsigned p = ebuf[base + i];
        atomicAdd(&cnt[(p >> 16) & 255], 1);
        atomicAdd(&cntc[p & 0xFFFFu], 1);           // col degree (moved from k_bin)
    }
    __syncthreads();
    if (t == 0) {
        int s = 0;
        #pragma unroll
        for (int r = 0; r < RPB; ++r) { excl[r] = s; s += cnt[r]; }
    }
    __syncthreads();
    const int row0 = b * RPB;
    if (t < RPB && row0 + t < N) {
        begN[row0 + t] = base + excl[t];
        endN[row0 + t] = base + excl[t] + cnt[t];
    }
    if (t < RPB) cnt[t] = excl[t];   // reuse as cursor
    __syncthreads();
    for (int i = t; i < m; i += 1024) {
        unsigned p = ebuf[base + i];
        int pos = atomicAdd(&cnt[(p >> 16) & 255], 1);
        ecol[base + pos] = (unsigned short)(p & 0xFFFFu);
    }
}

// --- gemm: xlb = bf16(x @ W + b) -----------------------------------------
#define GEMM_R 8
__global__ __launch_bounds__(128) void k_gemm(const float* __restrict__ x,
                                              const float* __restrict__ W,
                                              const float* __restrict__ b,
                                              unsigned short* __restrict__ xlb,
                                              int N) {
    __shared__ float xs[GEMM_R][D];
    const int c  = threadIdx.x;
    const int r0 = blockIdx.x * GEMM_R;
    #pragma unroll
    for (int r = 0; r < GEMM_R; ++r) {
        int row = r0 + r;
        xs[r][c] = (row < N) ? x[row * D + c] : 0.0f;
    }
    __syncthreads();

    float acc[GEMM_R];
    const float bc = b[c];
    #pragma unroll
    for (int r = 0; r < GEMM_R; ++r) acc[r] = bc;

    for (int k = 0; k < D; k += 4) {
        const float w0 = W[(k + 0) * D + c];
        const float w1 = W[(k + 1) * D + c];
        const float w2 = W[(k + 2) * D + c];
        const float w3 = W[(k + 3) * D + c];
        #pragma unroll
        for (int r = 0; r < GEMM_R; ++r) {
            const float4 xv = *reinterpret_cast<const float4*>(&xs[r][k]);
            acc[r] = fmaf(xv.x, w0, acc[r]);
            acc[r] = fmaf(xv.y, w1, acc[r]);
            acc[r] = fmaf(xv.z, w2, acc[r]);
            acc[r] = fmaf(xv.w, w3, acc[r]);
        }
    }
    #pragma unroll
    for (int r = 0; r < GEMM_R; ++r) {
        int row = r0 + r;
        if (row < N) xlb[row * D + c] = f2bf(acc[r]);
    }
}

// --- wave-per-node gather-reduce (no LDS, no barriers) -------------------
__global__ __launch_bounds__(256) void k_reduce(const int* __restrict__ begN,
                                                const int* __restrict__ endN,
                                                const unsigned short* __restrict__ ecol,
                                                const float* __restrict__ dis,
                                                const unsigned short* __restrict__ xlb,
                                                float* __restrict__ out, int N) {
    const int wave = threadIdx.x >> 6;
    const int lane = threadIdx.x & 63;
    const int i = blockIdx.x * 4 + wave;
    if (i >= N) return;
    const float di = dis[i];

    // self loop
    const ushort2 sv = *reinterpret_cast<const ushort2*>(xlb + (size_t)i * D + lane * 2);
    float ax = di * di * bf2f(sv.x);
    float ay = di * di * bf2f(sv.y);

    const int beg = begN[i], end = endN[i];
    for (int base = beg; base < end; base += 64) {
        int m = end - base; if (m > 64) m = 64;
        int   c = 0;
        float n = 0.0f;
        if (lane < m) {
            c = ecol[base + lane];
            n = di * dis[c];
        }
        for (int j = 0; j < m; j += 8) {
            float vx[8], vy[8], nn[8];
            #pragma unroll
            for (int u = 0; u < 8; ++u) {          // 8 independent 256B gathers
                int cc = __shfl(c, j + u);         // lanes >= m carry c=0,n=0
                ushort2 s = *reinterpret_cast<const ushort2*>(xlb + (size_t)cc * D + lane * 2);
                vx[u] = bf2f(s.x);
                vy[u] = bf2f(s.y);
                nn[u] = __shfl(n, j + u);
            }
            #pragma unroll
            for (int u = 0; u < 8; ++u) {
                ax = fmaf(nn[u], vx[u], ax);
                ay = fmaf(nn[u], vy[u], ay);
            }
        }
    }
    *reinterpret_cast<float2*>(out + (size_t)i * D + lane * 2) = make_float2(ax, ay);
}

// ======================= fallback (R1 atomic path) =======================
__global__ __launch_bounds__(256) void k_zero(int* __restrict__ p, int n) {
    int i = blockIdx.x * 256 + threadIdx.x;
    if (i < n) p[i] = 0;
}
__global__ __launch_bounds__(256) void k_deg(const int* __restrict__ cols,
                                             int* __restrict__ cntc, int E) {
    int e = blockIdx.x * 256 + threadIdx.x;
    if (e < E) atomicAdd(&cntc[cols[e]], 1);
}
__global__ __launch_bounds__(128) void k_gemmf(const float* __restrict__ x,
                                               const float* __restrict__ W,
                                               const float* __restrict__ b,
                                               float* __restrict__ xl, int N) {
    __shared__ float xs[GEMM_R][D];
    const int c  = threadIdx.x;
    const int r0 = blockIdx.x * GEMM_R;
    #pragma unroll
    for (int r = 0; r < GEMM_R; ++r) {
        int row = r0 + r;
        xs[r][c] = (row < N) ? x[row * D + c] : 0.0f;
    }
    __syncthreads();
    float acc[GEMM_R];
    const float bc = b[c];
    #pragma unroll
    for (int r = 0; r < GEMM_R; ++r) acc[r] = bc;
    for (int k = 0; k < D; k += 4) {
        const float w0 = W[(k + 0) * D + c];
        const float w1 = W[(k + 1) * D + c];
        const float w2 = W[(k + 2) * D + c];
        const float w3 = W[(k + 3) * D + c];
        #pragma unroll
        for (int r = 0; r < GEMM_R; ++r) {
            const float4 xv = *reinterpret_cast<const float4*>(&xs[r][k]);
            acc[r] = fmaf(xv.x, w0, acc[r]);
            acc[r] = fmaf(xv.y, w1, acc[r]);
            acc[r] = fmaf(xv.z, w2, acc[r]);
            acc[r] = fmaf(xv.w, w3, acc[r]);
        }
    }
    #pragma unroll
    for (int r = 0; r < GEMM_R; ++r) {
        int row = r0 + r;
        if (row < N) xl[row * D + c] = acc[r];
    }
}
__global__ __launch_bounds__(256) void k_self(const float* __restrict__ xl,
                                              const float* __restrict__ dis,
                                              float* __restrict__ out, int N) {
    int gid = blockIdx.x * 256 + threadIdx.x;
    int i = gid >> 7;
    if (i < N) {
        float d = dis[i];
        out[gid] = d * d * xl[gid];
    }
}
__global__ __launch_bounds__(256) void k_scatter(const int* __restrict__ rows,
                                                 const int* __restrict__ cols,
                                                 const float* __restrict__ dis,
                                                 const float* __restrict__ xl,
                                                 float* __restrict__ out, int E) {
    long long gid = (long long)blockIdx.x * 256 + threadIdx.x;
    int e    = (int)(gid >> 6);
    int lane = (int)(gid & 63);
    if (e >= E) return;
    const int row = rows[e];
    const int col = cols[e];
    const float nrm = dis[row] * dis[col];
    atomicAdd(&out[row * D + lane],      nrm * xl[col * D + lane]);
    atomicAdd(&out[row * D + 64 + lane], nrm * xl[col * D + 64 + lane]);
}

// ======================= launch ==========================================
extern "C" void kernel_launch(void* const* d_in, const int* in_sizes, int n_in,
                              void* d_out, int out_size, void* d_ws, size_t ws_size,
                              hipStream_t stream) {
    const float* x   = (const float*)d_in[0];
    const int*   ei  = (const int*)d_in[1];
    const float* W   = (const float*)d_in[2];
    const float* b   = (const float*)d_in[3];
    float*       out = (float*)d_out;

    const int N = in_sizes[0] / D;   // 50000
    const int E = in_sizes[1] / 2;   // 1.6M
    const int* rows = ei;
    const int* cols = ei + E;
    const int NB = (N + RPB - 1) / RPB;        // 196
    const int NT = (E + TILE - 1) / TILE;      // 196
    const int CAP = (((2 * E) / NB) + 63) / 64 * 64;   // 2x mean bucket, 64-aligned

    // ws layout
    char* p = (char*)d_ws;
    size_t off = 0;
    unsigned short* xlb  = (unsigned short*)(p + off); off += (size_t)N * D * 2;
    float*          dis  = (float*)(p + off);          off += (size_t)N * 4;
    int*            cntc = (int*)(p + off);            off += (size_t)N * 4;
    int*            bcur = (int*)(p + off);            off += (size_t)MAXB * 4;
    int*            begN = (int*)(p + off);            off += (size_t)N * 4;
    int*            endN = (int*)(p + off);            off += (size_t)N * 4;
    unsigned*       ebuf = (unsigned*)(p + off);       off += (size_t)NB * CAP * 4;
    unsigned short* ecol = (unsigned short*)(p + off); off += (size_t)NB * CAP * 2;

    const int gN = (N + 255) / 256;
    const int gE = (E + 255) / 256;

    if (N <= 65536 && NB <= MAXB && ws_size >= off) {
        k_init  <<<gN, 256, 0, stream>>>(cntc, bcur, N, NB, CAP);
        k_bin   <<<NT, BINB, 0, stream>>>(rows, cols, bcur, ebuf, E, NB, CAP);
        k_sort  <<<NB, 1024, 0, stream>>>(bcur, ebuf, cntc, ecol, begN, endN, N, CAP);
        k_dis   <<<gN, 256, 0, stream>>>(cntc, dis, N);
        k_gemm  <<<(N + GEMM_R - 1) / GEMM_R, 128, 0, stream>>>(x, W, b, xlb, N);
        k_reduce<<<(N + 3) / 4, 256, 0, stream>>>(begN, endN, ecol, dis, xlb, out, N);
    } else {
        // fallback: R1 atomic scatter path (fp32 xl)
        char* q = (char*)d_ws;
        float* xl   = (float*)q;
        float* disF = (float*)(q + (size_t)N * D * 4);
        int*   cc   = (int*)(q + (size_t)N * D * 4 + (size_t)N * 4);
        k_zero <<<gN, 256, 0, stream>>>(cc, N);
        k_deg  <<<gE, 256, 0, stream>>>(cols, cc, E);
        k_dis  <<<gN, 256, 0, stream>>>(cc, disF, N);
        k_gemmf<<<(N + GEMM_R - 1) / GEMM_R, 128, 0, stream>>>(x, W, b, xl, N);
        k_self <<<((N * D) + 255) / 256, 256, 0, stream>>>(xl, disF, out, N);
        long long st = (long long)E * 64;
        k_scatter<<<(int)((st + 255) / 256), 256, 0, stream>>>(rows, cols, disF, xl, out, E);
    }
}

// Round 8
// 216.738 us; speedup vs baseline: 1.2099x; 1.2099x over previous
//
#include <hip/hip_runtime.h>
#include <hip/hip_bf16.h>

// GCNConv: out[i] = sum_{e: row[e]=i} dis[row]*dis[col]*xl[col] + dis[i]^2*xl[i]
// N=50000, E=1.6M, D=128, fp32 in/out.
//
// R7 -> R8: model: random L2 transactions run at ~40G/s device-wide --
// k_sort's 1.6M random cntc atomics + 1.6M scattered 2B ecol stores (53MB
// writeback amp) = its 79us. Fix:
//  - k_split: per-bucket counting sort staged in LDS (random scatter hits
//    LDS, free), sorted ecol written LINEARLY coalesced. No global atomics.
//  - k_deg2: segmented LDS histogram for degree (4 coalesced sweeps of cols,
//    merge via coalesced atomics) instead of 1.6M random atomics.

#define D     128
#define TILE  8192
#define BINB  1024      // k_bin block size
#define RPB   256       // rows per bucket
#define MAXB  256       // bucket id must fit 8 bits
#define SPLIT_CAP 16384 // LDS sort capacity (= CAP for N=50000/E=1.6M)
#define DSEG  4         // degree histogram segments
#define DTIL  32        // degree histogram tiles over E

static __device__ __forceinline__ unsigned short f2bf(float f) {
    unsigned u = __float_as_uint(f);
    u = (u + 0x7FFFu + ((u >> 16) & 1u)) >> 16;   // RNE
    return (unsigned short)u;
}
static __device__ __forceinline__ float bf2f(unsigned short s) {
    return __uint_as_float(((unsigned)s) << 16);
}

// --- init: cntc = 0, bcur[b] = b*CAP -------------------------------------
__global__ __launch_bounds__(256) void k_init(int* __restrict__ cntc,
                                              int* __restrict__ bcur,
                                              int N, int NB, int CAP) {
    int i = blockIdx.x * 256 + threadIdx.x;
    if (i < N) cntc[i] = 0;
    if (i < NB) bcur[i] = i * CAP;
}

// --- single-pass bin into fixed-stride bucket regions --------------------
__global__ __launch_bounds__(BINB) void k_bin(const int* __restrict__ rows,
                                              const int* __restrict__ cols,
                                              int* __restrict__ bcur,
                                              unsigned* __restrict__ ebuf,
                                              int E, int NB, int CAP) {
    __shared__ int lcnt[MAXB];
    __shared__ int lbase[MAXB];
    const int t = threadIdx.x;
    const int base = blockIdx.x * TILE;
    int m = E - base; if (m > TILE) m = TILE;

    unsigned p[TILE / BINB];
    #pragma unroll
    for (int it = 0; it < TILE / BINB; ++it) {
        int i = it * BINB + t;
        if (i < m) {
            unsigned r = (unsigned)rows[base + i];
            unsigned c = (unsigned)cols[base + i];
            p[it] = c | ((r & 255u) << 16) | ((r >> 8) << 24);
        }
    }
    for (int b = t; b < NB; b += BINB) lcnt[b] = 0;
    __syncthreads();
    #pragma unroll
    for (int it = 0; it < TILE / BINB; ++it) {
        int i = it * BINB + t;
        if (i < m) atomicAdd(&lcnt[p[it] >> 24], 1);
    }
    __syncthreads();
    for (int b = t; b < NB; b += BINB) {
        int c = lcnt[b];
        lbase[b] = c ? atomicAdd(&bcur[b], c) : 0;
        lcnt[b] = 0;
    }
    __syncthreads();
    #pragma unroll
    for (int it = 0; it < TILE / BINB; ++it) {
        int i = it * BINB + t;
        if (i < m) {
            int bk = p[it] >> 24;
            int r  = atomicAdd(&lcnt[bk], 1);
            int pos = lbase[bk] + r;
            if (pos < (bk + 1) * CAP)               // overflow guard (never fires)
                ebuf[pos] = p[it] & 0xFFFFFFu;      // col | rowlocal<<16
        }
    }
}

// --- degree: segmented LDS histogram (no random global atomics) ----------
__global__ __launch_bounds__(1024) void k_deg2(const int* __restrict__ cols,
                                               int* __restrict__ cntc,
                                               int E, int N) {
    const int segw = (N + DSEG - 1) / DSEG;         // 12500
    __shared__ int h[12544];                        // >= segw
    const int seg  = blockIdx.x & (DSEG - 1);
    const int tile = blockIdx.x >> 2;               // DSEG==4
    const int lo = seg * segw;
    const int hi = min(lo + segw, N);
    const int w  = hi - lo;
    for (int i = threadIdx.x; i < w; i += 1024) h[i] = 0;
    __syncthreads();
    const int per = (E + DTIL - 1) / DTIL;
    const int beg = tile * per;
    const int end = min(beg + per, E);
    for (int i = beg + threadIdx.x; i < end; i += 1024) {
        int c = cols[i];
        if (c >= lo && c < hi) atomicAdd(&h[c - lo], 1);
    }
    __syncthreads();
    for (int i = threadIdx.x; i < w; i += 1024) {
        int v = h[i];
        if (v) atomicAdd(&cntc[lo + i], v);         // coalesced merge
    }
}

// --- dis = rsqrt(deg_col + 1) --------------------------------------------
__global__ __launch_bounds__(256) void k_dis(const int* __restrict__ cntc,
                                             float* __restrict__ dis, int N) {
    int i = blockIdx.x * 256 + threadIdx.x;
    if (i < N) dis[i] = rsqrtf((float)(cntc[i] + 1));
}

// --- per-bucket counting sort staged in LDS, linear global writes --------
__global__ __launch_bounds__(1024) void k_split(const int* __restrict__ bcur,
                                                const unsigned* __restrict__ ebuf,
                                                unsigned short* __restrict__ ecol,
                                                int* __restrict__ begN,
                                                int* __restrict__ endN,
                                                int N, int CAP) {
    __shared__ unsigned short sorted[SPLIT_CAP];    // 32 KB
    __shared__ int cnt[RPB];
    __shared__ int excl[RPB];
    __shared__ int cur[RPB];
    const int b = blockIdx.x, t = threadIdx.x;
    const int base = b * CAP;
    int m = bcur[b] - base; if (m > CAP) m = CAP;
    if (t < RPB) cnt[t] = 0;
    __syncthreads();
    for (int i = t; i < m; i += 1024)
        atomicAdd(&cnt[(ebuf[base + i] >> 16) & 255], 1);
    __syncthreads();
    if (t == 0) {
        int s = 0;
        #pragma unroll
        for (int r = 0; r < RPB; ++r) { excl[r] = s; s += cnt[r]; }
    }
    __syncthreads();
    const int row0 = b * RPB;
    if (t < RPB) {
        cur[t] = excl[t];
        if (row0 + t < N) {
            begN[row0 + t] = base + excl[t];
            endN[row0 + t] = base + excl[t] + cnt[t];
        }
    }
    __syncthreads();
    for (int i = t; i < m; i += 1024) {
        unsigned p = ebuf[base + i];
        int pos = atomicAdd(&cur[(p >> 16) & 255], 1);
        sorted[pos] = (unsigned short)(p & 0xFFFFu);   // random scatter in LDS
    }
    __syncthreads();
    for (int i = t; i < m; i += 1024)
        ecol[base + i] = sorted[i];                     // linear coalesced write
}

// --- gemm: xlb = bf16(x @ W + b) -----------------------------------------
#define GEMM_R 8
__global__ __launch_bounds__(128) void k_gemm(const float* __restrict__ x,
                                              const float* __restrict__ W,
                                              const float* __restrict__ b,
                                              unsigned short* __restrict__ xlb,
                                              int N) {
    __shared__ float xs[GEMM_R][D];
    const int c  = threadIdx.x;
    const int r0 = blockIdx.x * GEMM_R;
    #pragma unroll
    for (int r = 0; r < GEMM_R; ++r) {
        int row = r0 + r;
        xs[r][c] = (row < N) ? x[row * D + c] : 0.0f;
    }
    __syncthreads();

    float acc[GEMM_R];
    const float bc = b[c];
    #pragma unroll
    for (int r = 0; r < GEMM_R; ++r) acc[r] = bc;

    for (int k = 0; k < D; k += 4) {
        const float w0 = W[(k + 0) * D + c];
        const float w1 = W[(k + 1) * D + c];
        const float w2 = W[(k + 2) * D + c];
        const float w3 = W[(k + 3) * D + c];
        #pragma unroll
        for (int r = 0; r < GEMM_R; ++r) {
            const float4 xv = *reinterpret_cast<const float4*>(&xs[r][k]);
            acc[r] = fmaf(xv.x, w0, acc[r]);
            acc[r] = fmaf(xv.y, w1, acc[r]);
            acc[r] = fmaf(xv.z, w2, acc[r]);
            acc[r] = fmaf(xv.w, w3, acc[r]);
        }
    }
    #pragma unroll
    for (int r = 0; r < GEMM_R; ++r) {
        int row = r0 + r;
        if (row < N) xlb[row * D + c] = f2bf(acc[r]);
    }
}

// --- wave-per-node gather-reduce (no LDS, no barriers) -------------------
__global__ __launch_bounds__(256) void k_reduce(const int* __restrict__ begN,
                                                const int* __restrict__ endN,
                                                const unsigned short* __restrict__ ecol,
                                                const float* __restrict__ dis,
                                                const unsigned short* __restrict__ xlb,
                                                float* __restrict__ out, int N) {
    const int wave = threadIdx.x >> 6;
    const int lane = threadIdx.x & 63;
    const int i = blockIdx.x * 4 + wave;
    if (i >= N) return;
    const float di = dis[i];

    // self loop
    const ushort2 sv = *reinterpret_cast<const ushort2*>(xlb + (size_t)i * D + lane * 2);
    float ax = di * di * bf2f(sv.x);
    float ay = di * di * bf2f(sv.y);

    const int beg = begN[i], end = endN[i];
    for (int base = beg; base < end; base += 64) {
        int m = end - base; if (m > 64) m = 64;
        int   c = 0;
        float n = 0.0f;
        if (lane < m) {
            c = ecol[base + lane];
            n = di * dis[c];
        }
        for (int j = 0; j < m; j += 8) {
            float vx[8], vy[8], nn[8];
            #pragma unroll
            for (int u = 0; u < 8; ++u) {          // 8 independent 256B gathers
                int cc = __shfl(c, j + u);         // lanes >= m carry c=0,n=0
                ushort2 s = *reinterpret_cast<const ushort2*>(xlb + (size_t)cc * D + lane * 2);
                vx[u] = bf2f(s.x);
                vy[u] = bf2f(s.y);
                nn[u] = __shfl(n, j + u);
            }
            #pragma unroll
            for (int u = 0; u < 8; ++u) {
                ax = fmaf(nn[u], vx[u], ax);
                ay = fmaf(nn[u], vy[u], ay);
            }
        }
    }
    *reinterpret_cast<float2*>(out + (size_t)i * D + lane * 2) = make_float2(ax, ay);
}

// ======================= fallback (R1 atomic path) =======================
__global__ __launch_bounds__(256) void k_zero(int* __restrict__ p, int n) {
    int i = blockIdx.x * 256 + threadIdx.x;
    if (i < n) p[i] = 0;
}
__global__ __launch_bounds__(256) void k_deg(const int* __restrict__ cols,
                                             int* __restrict__ cntc, int E) {
    int e = blockIdx.x * 256 + threadIdx.x;
    if (e < E) atomicAdd(&cntc[cols[e]], 1);
}
__global__ __launch_bounds__(128) void k_gemmf(const float* __restrict__ x,
                                               const float* __restrict__ W,
                                               const float* __restrict__ b,
                                               float* __restrict__ xl, int N) {
    __shared__ float xs[GEMM_R][D];
    const int c  = threadIdx.x;
    const int r0 = blockIdx.x * GEMM_R;
    #pragma unroll
    for (int r = 0; r < GEMM_R; ++r) {
        int row = r0 + r;
        xs[r][c] = (row < N) ? x[row * D + c] : 0.0f;
    }
    __syncthreads();
    float acc[GEMM_R];
    const float bc = b[c];
    #pragma unroll
    for (int r = 0; r < GEMM_R; ++r) acc[r] = bc;
    for (int k = 0; k < D; k += 4) {
        const float w0 = W[(k + 0) * D + c];
        const float w1 = W[(k + 1) * D + c];
        const float w2 = W[(k + 2) * D + c];
        const float w3 = W[(k + 3) * D + c];
        #pragma unroll
        for (int r = 0; r < GEMM_R; ++r) {
            const float4 xv = *reinterpret_cast<const float4*>(&xs[r][k]);
            acc[r] = fmaf(xv.x, w0, acc[r]);
            acc[r] = fmaf(xv.y, w1, acc[r]);
            acc[r] = fmaf(xv.z, w2, acc[r]);
            acc[r] = fmaf(xv.w, w3, acc[r]);
        }
    }
    #pragma unroll
    for (int r = 0; r < GEMM_R; ++r) {
        int row = r0 + r;
        if (row < N) xl[row * D + c] = acc[r];
    }
}
__global__ __launch_bounds__(256) void k_self(const float* __restrict__ xl,
                                              const float* __restrict__ dis,
                                              float* __restrict__ out, int N) {
    int gid = blockIdx.x * 256 + threadIdx.x;
    int i = gid >> 7;
    if (i < N) {
        float d = dis[i];
        out[gid] = d * d * xl[gid];
    }
}
__global__ __launch_bounds__(256) void k_scatter(const int* __restrict__ rows,
                                                 const int* __restrict__ cols,
                                                 const float* __restrict__ dis,
                                                 const float* __restrict__ xl,
                                                 float* __restrict__ out, int E) {
    long long gid = (long long)blockIdx.x * 256 + threadIdx.x;
    int e    = (int)(gid >> 6);
    int lane = (int)(gid & 63);
    if (e >= E) return;
    const int row = rows[e];
    const int col = cols[e];
    const float nrm = dis[row] * dis[col];
    atomicAdd(&out[row * D + lane],      nrm * xl[col * D + lane]);
    atomicAdd(&out[row * D + 64 + lane], nrm * xl[col * D + 64 + lane]);
}

// ======================= launch ==========================================
extern "C" void kernel_launch(void* const* d_in, const int* in_sizes, int n_in,
                              void* d_out, int out_size, void* d_ws, size_t ws_size,
                              hipStream_t stream) {
    const float* x   = (const float*)d_in[0];
    const int*   ei  = (const int*)d_in[1];
    const float* W   = (const float*)d_in[2];
    const float* b   = (const float*)d_in[3];
    float*       out = (float*)d_out;

    const int N = in_sizes[0] / D;   // 50000
    const int E = in_sizes[1] / 2;   // 1.6M
    const int* rows = ei;
    const int* cols = ei + E;
    const int NB = (N + RPB - 1) / RPB;        // 196
    const int NT = (E + TILE - 1) / TILE;      // 196
    const int CAP = (((2 * E) / NB) + 63) / 64 * 64;   // 2x mean bucket -> 16384

    // ws layout
    char* p = (char*)d_ws;
    size_t off = 0;
    unsigned short* xlb  = (unsigned short*)(p + off); off += (size_t)N * D * 2;
    float*          dis  = (float*)(p + off);          off += (size_t)N * 4;
    int*            cntc = (int*)(p + off);            off += (size_t)N * 4;
    int*            bcur = (int*)(p + off);            off += (size_t)MAXB * 4;
    int*            begN = (int*)(p + off);            off += (size_t)N * 4;
    int*            endN = (int*)(p + off);            off += (size_t)N * 4;
    unsigned*       ebuf = (unsigned*)(p + off);       off += (size_t)NB * CAP * 4;
    unsigned short* ecol = (unsigned short*)(p + off); off += (size_t)NB * CAP * 2;

    const int gN = (N + 255) / 256;
    const int gE = (E + 255) / 256;

    if (N <= 65536 && NB <= MAXB && CAP <= SPLIT_CAP && ws_size >= off) {
        k_init  <<<gN, 256, 0, stream>>>(cntc, bcur, N, NB, CAP);
        k_bin   <<<NT, BINB, 0, stream>>>(rows, cols, bcur, ebuf, E, NB, CAP);
        k_deg2  <<<DTIL * DSEG, 1024, 0, stream>>>(cols, cntc, E, N);
        k_dis   <<<gN, 256, 0, stream>>>(cntc, dis, N);
        k_split <<<NB, 1024, 0, stream>>>(bcur, ebuf, ecol, begN, endN, N, CAP);
        k_gemm  <<<(N + GEMM_R - 1) / GEMM_R, 128, 0, stream>>>(x, W, b, xlb, N);
        k_reduce<<<(N + 3) / 4, 256, 0, stream>>>(begN, endN, ecol, dis, xlb, out, N);
    } else {
        // fallback: R1 atomic scatter path (fp32 xl)
        char* q = (char*)d_ws;
        float* xl   = (float*)q;
        float* disF = (float*)(q + (size_t)N * D * 4);
        int*   cc   = (int*)(q + (size_t)N * D * 4 + (size_t)N * 4);
        k_zero <<<gN, 256, 0, stream>>>(cc, N);
        k_deg  <<<gE, 256, 0, stream>>>(cols, cc, E);
        k_dis  <<<gN, 256, 0, stream>>>(cc, disF, N);
        k_gemmf<<<(N + GEMM_R - 1) / GEMM_R, 128, 0, stream>>>(x, W, b, xl, N);
        k_self <<<((N * D) + 255) / 256, 256, 0, stream>>>(xl, disF, out, N);
        long long st = (long long)E * 64;
        k_scatter<<<(int)((st + 255) / 256), 256, 0, stream>>>(rows, cols, disF, xl, out, E);
    }
}

// Round 9
// 212.971 us; speedup vs baseline: 1.2313x; 1.0177x over previous
//
#include <hip/hip_runtime.h>
#include <hip/hip_bf16.h>

// GCNConv: out[i] = sum_{e: row[e]=i} dis[row]*dis[col]*xl[col] + dis[i]^2*xl[i]
// N=50000, E=1.6M, D=128, fp32 in/out.
//
// R8 -> R9: k_gemm was 51.7us of fp32 VALU (32 TF, VALUBusy 53%). Replace
// with MFMA bf16 GEMM (G10): 64x128 tile/block, W^T + x staged bf16 in LDS
// (stride 136 padding), wave = 16-row strip, 4 K-steps x 8 n-tiles of
// mfma_f32_16x16x32_bf16 (m89-verified A/B/C layouts). Predicted ~10us.
// Error budget: +0.0003 absmax on out (neighbor averaging) -- margin ok.

#define D     128
#define TILE  8192
#define BINB  1024      // k_bin block size
#define RPB   256       // rows per bucket
#define MAXB  256       // bucket id must fit 8 bits
#define SPLIT_CAP 16384 // LDS sort capacity (= CAP for N=50000/E=1.6M)
#define DSEG  4         // degree histogram segments
#define DTIL  32        // degree histogram tiles over E

typedef short  bf16x8 __attribute__((ext_vector_type(8)));
typedef float  f32x4  __attribute__((ext_vector_type(4)));

static __device__ __forceinline__ unsigned short f2bf(float f) {
    unsigned u = __float_as_uint(f);
    u = (u + 0x7FFFu + ((u >> 16) & 1u)) >> 16;   // RNE
    return (unsigned short)u;
}
static __device__ __forceinline__ float bf2f(unsigned short s) {
    return __uint_as_float(((unsigned)s) << 16);
}

// --- init: cntc = 0, bcur[b] = b*CAP -------------------------------------
__global__ __launch_bounds__(256) void k_init(int* __restrict__ cntc,
                                              int* __restrict__ bcur,
                                              int N, int NB, int CAP) {
    int i = blockIdx.x * 256 + threadIdx.x;
    if (i < N) cntc[i] = 0;
    if (i < NB) bcur[i] = i * CAP;
}

// --- single-pass bin into fixed-stride bucket regions --------------------
__global__ __launch_bounds__(BINB) void k_bin(const int* __restrict__ rows,
                                              const int* __restrict__ cols,
                                              int* __restrict__ bcur,
                                              unsigned* __restrict__ ebuf,
                                              int E, int NB, int CAP) {
    __shared__ int lcnt[MAXB];
    __shared__ int lbase[MAXB];
    const int t = threadIdx.x;
    const int base = blockIdx.x * TILE;
    int m = E - base; if (m > TILE) m = TILE;

    unsigned p[TILE / BINB];
    #pragma unroll
    for (int it = 0; it < TILE / BINB; ++it) {
        int i = it * BINB + t;
        if (i < m) {
            unsigned r = (unsigned)rows[base + i];
            unsigned c = (unsigned)cols[base + i];
            p[it] = c | ((r & 255u) << 16) | ((r >> 8) << 24);
        }
    }
    for (int b = t; b < NB; b += BINB) lcnt[b] = 0;
    __syncthreads();
    #pragma unroll
    for (int it = 0; it < TILE / BINB; ++it) {
        int i = it * BINB + t;
        if (i < m) atomicAdd(&lcnt[p[it] >> 24], 1);
    }
    __syncthreads();
    for (int b = t; b < NB; b += BINB) {
        int c = lcnt[b];
        lbase[b] = c ? atomicAdd(&bcur[b], c) : 0;
        lcnt[b] = 0;
    }
    __syncthreads();
    #pragma unroll
    for (int it = 0; it < TILE / BINB; ++it) {
        int i = it * BINB + t;
        if (i < m) {
            int bk = p[it] >> 24;
            int r  = atomicAdd(&lcnt[bk], 1);
            int pos = lbase[bk] + r;
            if (pos < (bk + 1) * CAP)               // overflow guard (never fires)
                ebuf[pos] = p[it] & 0xFFFFFFu;      // col | rowlocal<<16
        }
    }
}

// --- degree: segmented LDS histogram (no random global atomics) ----------
__global__ __launch_bounds__(1024) void k_deg2(const int* __restrict__ cols,
                                               int* __restrict__ cntc,
                                               int E, int N) {
    const int segw = (N + DSEG - 1) / DSEG;         // 12500
    __shared__ int h[12544];                        // >= segw
    const int seg  = blockIdx.x & (DSEG - 1);
    const int tile = blockIdx.x >> 2;               // DSEG==4
    const int lo = seg * segw;
    const int hi = min(lo + segw, N);
    const int w  = hi - lo;
    for (int i = threadIdx.x; i < w; i += 1024) h[i] = 0;
    __syncthreads();
    const int per = (E + DTIL - 1) / DTIL;
    const int beg = tile * per;
    const int end = min(beg + per, E);
    for (int i = beg + threadIdx.x; i < end; i += 1024) {
        int c = cols[i];
        if (c >= lo && c < hi) atomicAdd(&h[c - lo], 1);
    }
    __syncthreads();
    for (int i = threadIdx.x; i < w; i += 1024) {
        int v = h[i];
        if (v) atomicAdd(&cntc[lo + i], v);         // coalesced merge
    }
}

// --- dis = rsqrt(deg_col + 1) --------------------------------------------
__global__ __launch_bounds__(256) void k_dis(const int* __restrict__ cntc,
                                             float* __restrict__ dis, int N) {
    int i = blockIdx.x * 256 + threadIdx.x;
    if (i < N) dis[i] = rsqrtf((float)(cntc[i] + 1));
}

// --- per-bucket counting sort staged in LDS, linear global writes --------
__global__ __launch_bounds__(1024) void k_split(const int* __restrict__ bcur,
                                                const unsigned* __restrict__ ebuf,
                                                unsigned short* __restrict__ ecol,
                                                int* __restrict__ begN,
                                                int* __restrict__ endN,
                                                int N, int CAP) {
    __shared__ unsigned short sorted[SPLIT_CAP];    // 32 KB
    __shared__ int cnt[RPB];
    __shared__ int excl[RPB];
    __shared__ int cur[RPB];
    const int b = blockIdx.x, t = threadIdx.x;
    const int base = b * CAP;
    int m = bcur[b] - base; if (m > CAP) m = CAP;
    if (t < RPB) cnt[t] = 0;
    __syncthreads();
    for (int i = t; i < m; i += 1024)
        atomicAdd(&cnt[(ebuf[base + i] >> 16) & 255], 1);
    __syncthreads();
    if (t == 0) {
        int s = 0;
        #pragma unroll
        for (int r = 0; r < RPB; ++r) { excl[r] = s; s += cnt[r]; }
    }
    __syncthreads();
    const int row0 = b * RPB;
    if (t < RPB) {
        cur[t] = excl[t];
        if (row0 + t < N) {
            begN[row0 + t] = base + excl[t];
            endN[row0 + t] = base + excl[t] + cnt[t];
        }
    }
    __syncthreads();
    for (int i = t; i < m; i += 1024) {
        unsigned p = ebuf[base + i];
        int pos = atomicAdd(&cur[(p >> 16) & 255], 1);
        sorted[pos] = (unsigned short)(p & 0xFFFFu);   // random scatter in LDS
    }
    __syncthreads();
    for (int i = t; i < m; i += 1024)
        ecol[base + i] = sorted[i];                     // linear coalesced write
}

// --- MFMA bf16 GEMM: xlb = bf16(x @ W + b), 64x128 tile per block --------
__global__ __launch_bounds__(256) void k_gemm(const float* __restrict__ x,
                                              const float* __restrict__ W,
                                              const float* __restrict__ bia,
                                              unsigned short* __restrict__ xlb,
                                              int N) {
    __shared__ unsigned short wt[128][136];   // W^T, pad->16B-aligned rows
    __shared__ unsigned short xs[64][136];    // x tile bf16
    const int t = threadIdx.x;
    const int row0 = blockIdx.x * 64;

    #pragma unroll
    for (int i = 0; i < 64; ++i) {            // stage W^T (coalesced read)
        int idx = i * 256 + t;                // 16384 elems
        int k = idx >> 7, n = idx & 127;
        wt[n][k] = f2bf(W[idx]);
    }
    #pragma unroll
    for (int i = 0; i < 32; ++i) {            // stage x tile
        int idx = i * 256 + t;                // 8192 elems
        int r = idx >> 7, c = idx & 127;
        int gr = row0 + r;
        xs[r][c] = (gr < N) ? f2bf(x[(size_t)gr * D + c]) : (unsigned short)0;
    }
    __syncthreads();

    const int w  = t >> 6, l = t & 63;
    const int m0 = w * 16;                    // wave's 16-row strip
    const int lm = l & 15, lq = l >> 4;

    f32x4 acc[8];
    #pragma unroll
    for (int nt = 0; nt < 8; ++nt) acc[nt] = (f32x4){0.f, 0.f, 0.f, 0.f};

    #pragma unroll
    for (int kk = 0; kk < 4; ++kk) {
        const int kof = kk * 32 + lq * 8;
        bf16x8 a = *(const bf16x8*)&xs[m0 + lm][kof];      // A[m][k]
        #pragma unroll
        for (int nt = 0; nt < 8; ++nt) {
            bf16x8 bb = *(const bf16x8*)&wt[nt * 16 + lm][kof];  // B[k][n]=Wt[n][k]
            acc[nt] = __builtin_amdgcn_mfma_f32_16x16x32_bf16(a, bb, acc[nt], 0, 0, 0);
        }
    }

    #pragma unroll
    for (int nt = 0; nt < 8; ++nt) {
        const int col = nt * 16 + lm;
        const float bc = bia[col];
        #pragma unroll
        for (int r = 0; r < 4; ++r) {          // C: row=lq*4+r, col=lm (m89)
            int grow = row0 + m0 + lq * 4 + r;
            if (grow < N) xlb[(size_t)grow * D + col] = f2bf(acc[nt][r] + bc);
        }
    }
}

// --- wave-per-node gather-reduce (no LDS, no barriers) -------------------
__global__ __launch_bounds__(256) void k_reduce(const int* __restrict__ begN,
                                                const int* __restrict__ endN,
                                                const unsigned short* __restrict__ ecol,
                                                const float* __restrict__ dis,
                                                const unsigned short* __restrict__ xlb,
                                                float* __restrict__ out, int N) {
    const int wave = threadIdx.x >> 6;
    const int lane = threadIdx.x & 63;
    const int i = blockIdx.x * 4 + wave;
    if (i >= N) return;
    const float di = dis[i];

    // self loop
    const ushort2 sv = *reinterpret_cast<const ushort2*>(xlb + (size_t)i * D + lane * 2);
    float ax = di * di * bf2f(sv.x);
    float ay = di * di * bf2f(sv.y);

    const int beg = begN[i], end = endN[i];
    for (int base = beg; base < end; base += 64) {
        int m = end - base; if (m > 64) m = 64;
        int   c = 0;
        float n = 0.0f;
        if (lane < m) {
            c = ecol[base + lane];
            n = di * dis[c];
        }
        for (int j = 0; j < m; j += 8) {
            float vx[8], vy[8], nn[8];
            #pragma unroll
            for (int u = 0; u < 8; ++u) {          // 8 independent 256B gathers
                int cc = __shfl(c, j + u);         // lanes >= m carry c=0,n=0
                ushort2 s = *reinterpret_cast<const ushort2*>(xlb + (size_t)cc * D + lane * 2);
                vx[u] = bf2f(s.x);
                vy[u] = bf2f(s.y);
                nn[u] = __shfl(n, j + u);
            }
            #pragma unroll
            for (int u = 0; u < 8; ++u) {
                ax = fmaf(nn[u], vx[u], ax);
                ay = fmaf(nn[u], vy[u], ay);
            }
        }
    }
    *reinterpret_cast<float2*>(out + (size_t)i * D + lane * 2) = make_float2(ax, ay);
}

// ======================= fallback (R1 atomic path) =======================
__global__ __launch_bounds__(256) void k_zero(int* __restrict__ p, int n) {
    int i = blockIdx.x * 256 + threadIdx.x;
    if (i < n) p[i] = 0;
}
__global__ __launch_bounds__(256) void k_deg(const int* __restrict__ cols,
                                             int* __restrict__ cntc, int E) {
    int e = blockIdx.x * 256 + threadIdx.x;
    if (e < E) atomicAdd(&cntc[cols[e]], 1);
}
#define GEMM_R 8
__global__ __launch_bounds__(128) void k_gemmf(const float* __restrict__ x,
                                               const float* __restrict__ W,
                                               const float* __restrict__ b,
                                               float* __restrict__ xl, int N) {
    __shared__ float xs[GEMM_R][D];
    const int c  = threadIdx.x;
    const int r0 = blockIdx.x * GEMM_R;
    #pragma unroll
    for (int r = 0; r < GEMM_R; ++r) {
        int row = r0 + r;
        xs[r][c] = (row < N) ? x[row * D + c] : 0.0f;
    }
    __syncthreads();
    float acc[GEMM_R];
    const float bc = b[c];
    #pragma unroll
    for (int r = 0; r < GEMM_R; ++r) acc[r] = bc;
    for (int k = 0; k < D; k += 4) {
        const float w0 = W[(k + 0) * D + c];
        const float w1 = W[(k + 1) * D + c];
        const float w2 = W[(k + 2) * D + c];
        const float w3 = W[(k + 3) * D + c];
        #pragma unroll
        for (int r = 0; r < GEMM_R; ++r) {
            const float4 xv = *reinterpret_cast<const float4*>(&xs[r][k]);
            acc[r] = fmaf(xv.x, w0, acc[r]);
            acc[r] = fmaf(xv.y, w1, acc[r]);
            acc[r] = fmaf(xv.z, w2, acc[r]);
            acc[r] = fmaf(xv.w, w3, acc[r]);
        }
    }
    #pragma unroll
    for (int r = 0; r < GEMM_R; ++r) {
        int row = r0 + r;
        if (row < N) xl[row * D + c] = acc[r];
    }
}
__global__ __launch_bounds__(256) void k_self(const float* __restrict__ xl,
                                              const float* __restrict__ dis,
                                              float* __restrict__ out, int N) {
    int gid = blockIdx.x * 256 + threadIdx.x;
    int i = gid >> 7;
    if (i < N) {
        float d = dis[i];
        out[gid] = d * d * xl[gid];
    }
}
__global__ __launch_bounds__(256) void k_scatter(const int* __restrict__ rows,
                                                 const int* __restrict__ cols,
                                                 const float* __restrict__ dis,
                                                 const float* __restrict__ xl,
                                                 float* __restrict__ out, int E) {
    long long gid = (long long)blockIdx.x * 256 + threadIdx.x;
    int e    = (int)(gid >> 6);
    int lane = (int)(gid & 63);
    if (e >= E) return;
    const int row = rows[e];
    const int col = cols[e];
    const float nrm = dis[row] * dis[col];
    atomicAdd(&out[row * D + lane],      nrm * xl[col * D + lane]);
    atomicAdd(&out[row * D + 64 + lane], nrm * xl[col * D + 64 + lane]);
}

// ======================= launch ==========================================
extern "C" void kernel_launch(void* const* d_in, const int* in_sizes, int n_in,
                              void* d_out, int out_size, void* d_ws, size_t ws_size,
                              hipStream_t stream) {
    const float* x   = (const float*)d_in[0];
    const int*   ei  = (const int*)d_in[1];
    const float* W   = (const float*)d_in[2];
    const float* b   = (const float*)d_in[3];
    float*       out = (float*)d_out;

    const int N = in_sizes[0] / D;   // 50000
    const int E = in_sizes[1] / 2;   // 1.6M
    const int* rows = ei;
    const int* cols = ei + E;
    const int NB = (N + RPB - 1) / RPB;        // 196
    const int NT = (E + TILE - 1) / TILE;      // 196
    const int CAP = (((2 * E) / NB) + 63) / 64 * 64;   // 2x mean bucket -> 16384

    // ws layout
    char* p = (char*)d_ws;
    size_t off = 0;
    unsigned short* xlb  = (unsigned short*)(p + off); off += (size_t)N * D * 2;
    float*          dis  = (float*)(p + off);          off += (size_t)N * 4;
    int*            cntc = (int*)(p + off);            off += (size_t)N * 4;
    int*            bcur = (int*)(p + off);            off += (size_t)MAXB * 4;
    int*            begN = (int*)(p + off);            off += (size_t)N * 4;
    int*            endN = (int*)(p + off);            off += (size_t)N * 4;
    unsigned*       ebuf = (unsigned*)(p + off);       off += (size_t)NB * CAP * 4;
    unsigned short* ecol = (unsigned short*)(p + off); off += (size_t)NB * CAP * 2;

    const int gN = (N + 255) / 256;
    const int gE = (E + 255) / 256;

    if (N <= 65536 && NB <= MAXB && CAP <= SPLIT_CAP && ws_size >= off) {
        k_init  <<<gN, 256, 0, stream>>>(cntc, bcur, N, NB, CAP);
        k_bin   <<<NT, BINB, 0, stream>>>(rows, cols, bcur, ebuf, E, NB, CAP);
        k_deg2  <<<DTIL * DSEG, 1024, 0, stream>>>(cols, cntc, E, N);
        k_dis   <<<gN, 256, 0, stream>>>(cntc, dis, N);
        k_split <<<NB, 1024, 0, stream>>>(bcur, ebuf, ecol, begN, endN, N, CAP);
        k_gemm  <<<(N + 63) / 64, 256, 0, stream>>>(x, W, b, xlb, N);
        k_reduce<<<(N + 3) / 4, 256, 0, stream>>>(begN, endN, ecol, dis, xlb, out, N);
    } else {
        // fallback: R1 atomic scatter path (fp32 xl)
        char* q = (char*)d_ws;
        float* xl   = (float*)q;
        float* disF = (float*)(q + (size_t)N * D * 4);
        int*   cc   = (int*)(q + (size_t)N * D * 4 + (size_t)N * 4);
        k_zero <<<gN, 256, 0, stream>>>(cc, N);
        k_deg  <<<gE, 256, 0, stream>>>(cols, cc, E);
        k_dis  <<<gN, 256, 0, stream>>>(cc, disF, N);
        k_gemmf<<<(N + GEMM_R - 1) / GEMM_R, 128, 0, stream>>>(x, W, b, xl, N);
        k_self <<<((N * D) + 255) / 256, 256, 0, stream>>>(xl, disF, out, N);
        long long st = (long long)E * 64;
        k_scatter<<<(int)((st + 255) / 256), 256, 0, stream>>>(rows, cols, disF, xl, out, E);
    }
}

// Round 10
// 197.365 us; speedup vs baseline: 1.3287x; 1.0791x over previous
//
#include <hip/hip_runtime.h>
#include <hip/hip_bf16.h>

// GCNConv: out[i] = sum_{e: row[e]=i} dis[row]*dis[col]*xl[col] + dis[i]^2*xl[i]
// N=50000, E=1.6M, D=128, fp32 in/out.
//
// R9 -> R10: MFMA gemm stalled at ~48us -- staging was 96 scalar loads +
// 96 scalar b16 LDS writes per thread (W re-converted per block, 8-way
// bank-conflicted transpose writes). Fix:
//  - k_prepw: W -> W^T bf16 once (32KB, ~2us)
//  - k_gemm staging: 8x ushort8+ds_write_b128 (W^T) + 8x float4+ds_write_b64
//    (x tile), all contiguous/conflict-free/16B-aligned. MFMA core unchanged.

#define D     128
#define TILE  8192
#define BINB  1024      // k_bin block size
#define RPB   256       // rows per bucket
#define MAXB  256       // bucket id must fit 8 bits
#define SPLIT_CAP 16384 // LDS sort capacity (= CAP for N=50000/E=1.6M)
#define DSEG  4         // degree histogram segments
#define DTIL  32        // degree histogram tiles over E

typedef short  bf16x8 __attribute__((ext_vector_type(8)));
typedef float  f32x4  __attribute__((ext_vector_type(4)));
typedef unsigned short us4 __attribute__((ext_vector_type(4)));
typedef unsigned short us8 __attribute__((ext_vector_type(8)));

static __device__ __forceinline__ unsigned short f2bf(float f) {
    unsigned u = __float_as_uint(f);
    u = (u + 0x7FFFu + ((u >> 16) & 1u)) >> 16;   // RNE
    return (unsigned short)u;
}
static __device__ __forceinline__ float bf2f(unsigned short s) {
    return __uint_as_float(((unsigned)s) << 16);
}

// --- init: cntc = 0, bcur[b] = b*CAP -------------------------------------
__global__ __launch_bounds__(256) void k_init(int* __restrict__ cntc,
                                              int* __restrict__ bcur,
                                              int N, int NB, int CAP) {
    int i = blockIdx.x * 256 + threadIdx.x;
    if (i < N) cntc[i] = 0;
    if (i < NB) bcur[i] = i * CAP;
}

// --- W (fp32 [k][n]) -> wtb (bf16 [n][k]) one-time -----------------------
__global__ __launch_bounds__(256) void k_prepw(const float* __restrict__ W,
                                               unsigned short* __restrict__ wtb) {
    int g = blockIdx.x * 256 + threadIdx.x;   // 16384 threads
    int n = g >> 7, k = g & 127;
    wtb[n * 128 + k] = f2bf(W[k * 128 + n]);
}

// --- single-pass bin into fixed-stride bucket regions --------------------
__global__ __launch_bounds__(BINB) void k_bin(const int* __restrict__ rows,
                                              const int* __restrict__ cols,
                                              int* __restrict__ bcur,
                                              unsigned* __restrict__ ebuf,
                                              int E, int NB, int CAP) {
    __shared__ int lcnt[MAXB];
    __shared__ int lbase[MAXB];
    const int t = threadIdx.x;
    const int base = blockIdx.x * TILE;
    int m = E - base; if (m > TILE) m = TILE;

    unsigned p[TILE / BINB];
    #pragma unroll
    for (int it = 0; it < TILE / BINB; ++it) {
        int i = it * BINB + t;
        if (i < m) {
            unsigned r = (unsigned)rows[base + i];
            unsigned c = (unsigned)cols[base + i];
            p[it] = c | ((r & 255u) << 16) | ((r >> 8) << 24);
        }
    }
    for (int b = t; b < NB; b += BINB) lcnt[b] = 0;
    __syncthreads();
    #pragma unroll
    for (int it = 0; it < TILE / BINB; ++it) {
        int i = it * BINB + t;
        if (i < m) atomicAdd(&lcnt[p[it] >> 24], 1);
    }
    __syncthreads();
    for (int b = t; b < NB; b += BINB) {
        int c = lcnt[b];
        lbase[b] = c ? atomicAdd(&bcur[b], c) : 0;
        lcnt[b] = 0;
    }
    __syncthreads();
    #pragma unroll
    for (int it = 0; it < TILE / BINB; ++it) {
        int i = it * BINB + t;
        if (i < m) {
            int bk = p[it] >> 24;
            int r  = atomicAdd(&lcnt[bk], 1);
            int pos = lbase[bk] + r;
            if (pos < (bk + 1) * CAP)               // overflow guard (never fires)
                ebuf[pos] = p[it] & 0xFFFFFFu;      // col | rowlocal<<16
        }
    }
}

// --- degree: segmented LDS histogram (no random global atomics) ----------
__global__ __launch_bounds__(1024) void k_deg2(const int* __restrict__ cols,
                                               int* __restrict__ cntc,
                                               int E, int N) {
    const int segw = (N + DSEG - 1) / DSEG;         // 12500
    __shared__ int h[12544];                        // >= segw
    const int seg  = blockIdx.x & (DSEG - 1);
    const int tile = blockIdx.x >> 2;               // DSEG==4
    const int lo = seg * segw;
    const int hi = min(lo + segw, N);
    const int w  = hi - lo;
    for (int i = threadIdx.x; i < w; i += 1024) h[i] = 0;
    __syncthreads();
    const int per = (E + DTIL - 1) / DTIL;
    const int beg = tile * per;
    const int end = min(beg + per, E);
    for (int i = beg + threadIdx.x; i < end; i += 1024) {
        int c = cols[i];
        if (c >= lo && c < hi) atomicAdd(&h[c - lo], 1);
    }
    __syncthreads();
    for (int i = threadIdx.x; i < w; i += 1024) {
        int v = h[i];
        if (v) atomicAdd(&cntc[lo + i], v);         // coalesced merge
    }
}

// --- dis = rsqrt(deg_col + 1) --------------------------------------------
__global__ __launch_bounds__(256) void k_dis(const int* __restrict__ cntc,
                                             float* __restrict__ dis, int N) {
    int i = blockIdx.x * 256 + threadIdx.x;
    if (i < N) dis[i] = rsqrtf((float)(cntc[i] + 1));
}

// --- per-bucket counting sort staged in LDS, linear global writes --------
__global__ __launch_bounds__(1024) void k_split(const int* __restrict__ bcur,
                                                const unsigned* __restrict__ ebuf,
                                                unsigned short* __restrict__ ecol,
                                                int* __restrict__ begN,
                                                int* __restrict__ endN,
                                                int N, int CAP) {
    __shared__ unsigned short sorted[SPLIT_CAP];    // 32 KB
    __shared__ int cnt[RPB];
    __shared__ int excl[RPB];
    __shared__ int cur[RPB];
    const int b = blockIdx.x, t = threadIdx.x;
    const int base = b * CAP;
    int m = bcur[b] - base; if (m > CAP) m = CAP;
    if (t < RPB) cnt[t] = 0;
    __syncthreads();
    for (int i = t; i < m; i += 1024)
        atomicAdd(&cnt[(ebuf[base + i] >> 16) & 255], 1);
    __syncthreads();
    if (t == 0) {
        int s = 0;
        #pragma unroll
        for (int r = 0; r < RPB; ++r) { excl[r] = s; s += cnt[r]; }
    }
    __syncthreads();
    const int row0 = b * RPB;
    if (t < RPB) {
        cur[t] = excl[t];
        if (row0 + t < N) {
            begN[row0 + t] = base + excl[t];
            endN[row0 + t] = base + excl[t] + cnt[t];
        }
    }
    __syncthreads();
    for (int i = t; i < m; i += 1024) {
        unsigned p = ebuf[base + i];
        int pos = atomicAdd(&cur[(p >> 16) & 255], 1);
        sorted[pos] = (unsigned short)(p & 0xFFFFu);   // random scatter in LDS
    }
    __syncthreads();
    for (int i = t; i < m; i += 1024)
        ecol[base + i] = sorted[i];                     // linear coalesced write
}

// --- MFMA bf16 GEMM: xlb = bf16(x @ W + b), 64x128 tile per block --------
// staging fully vectorized; W^T pre-converted to bf16 (wtb).
__global__ __launch_bounds__(256) void k_gemm(const float* __restrict__ x,
                                              const unsigned short* __restrict__ wtb,
                                              const float* __restrict__ bia,
                                              unsigned short* __restrict__ xlb,
                                              int N) {
    __shared__ unsigned short wt[128][136];   // W^T bf16, pad 8 -> 16B-aligned rows
    __shared__ unsigned short xs[64][136];    // x tile bf16
    const int t = threadIdx.x;
    const int row0 = blockIdx.x * 64;

    // stage W^T: 2048 ushort8 chunks; contiguous ds_write_b128
    #pragma unroll
    for (int i = 0; i < 8; ++i) {
        int j = i * 256 + t;                  // chunk id
        int n = j >> 4, k8 = j & 15;
        us8 v = *(const us8*)&wtb[j * 8];
        *(us8*)&wt[n][k8 * 8] = v;
    }
    // stage x tile: 2048 float4 chunks -> ushort4; contiguous ds_write_b64
    #pragma unroll
    for (int i = 0; i < 8; ++i) {
        int j = i * 256 + t;                  // float4 id
        int r = j >> 5, c4 = j & 31;
        int gr = row0 + r;
        us4 o = (us4){0, 0, 0, 0};
        if (gr < N) {
            float4 v = *(const float4*)&x[(size_t)gr * D + c4 * 4];
            o = (us4){f2bf(v.x), f2bf(v.y), f2bf(v.z), f2bf(v.w)};
        }
        *(us4*)&xs[r][c4 * 4] = o;
    }
    __syncthreads();

    const int w  = t >> 6, l = t & 63;
    const int m0 = w * 16;                    // wave's 16-row strip
    const int lm = l & 15, lq = l >> 4;

    f32x4 acc[8];
    #pragma unroll
    for (int nt = 0; nt < 8; ++nt) acc[nt] = (f32x4){0.f, 0.f, 0.f, 0.f};

    #pragma unroll
    for (int kk = 0; kk < 4; ++kk) {
        const int kof = kk * 32 + lq * 8;
        bf16x8 a = *(const bf16x8*)&xs[m0 + lm][kof];      // A[m][k]
        #pragma unroll
        for (int nt = 0; nt < 8; ++nt) {
            bf16x8 bb = *(const bf16x8*)&wt[nt * 16 + lm][kof];  // B[k][n]=Wt[n][k]
            acc[nt] = __builtin_amdgcn_mfma_f32_16x16x32_bf16(a, bb, acc[nt], 0, 0, 0);
        }
    }

    #pragma unroll
    for (int nt = 0; nt < 8; ++nt) {
        const int col = nt * 16 + lm;
        const float bc = bia[col];
        #pragma unroll
        for (int r = 0; r < 4; ++r) {          // C: row=lq*4+r, col=lm (m89)
            int grow = row0 + m0 + lq * 4 + r;
            if (grow < N) xlb[(size_t)grow * D + col] = f2bf(acc[nt][r] + bc);
        }
    }
}

// --- wave-per-node gather-reduce (no LDS, no barriers) -------------------
__global__ __launch_bounds__(256) void k_reduce(const int* __restrict__ begN,
                                                const int* __restrict__ endN,
                                                const unsigned short* __restrict__ ecol,
                                                const float* __restrict__ dis,
                                                const unsigned short* __restrict__ xlb,
                                                float* __restrict__ out, int N) {
    const int wave = threadIdx.x >> 6;
    const int lane = threadIdx.x & 63;
    const int i = blockIdx.x * 4 + wave;
    if (i >= N) return;
    const float di = dis[i];

    // self loop
    const ushort2 sv = *reinterpret_cast<const ushort2*>(xlb + (size_t)i * D + lane * 2);
    float ax = di * di * bf2f(sv.x);
    float ay = di * di * bf2f(sv.y);

    const int beg = begN[i], end = endN[i];
    for (int base = beg; base < end; base += 64) {
        int m = end - base; if (m > 64) m = 64;
        int   c = 0;
        float n = 0.0f;
        if (lane < m) {
            c = ecol[base + lane];
            n = di * dis[c];
        }
        for (int j = 0; j < m; j += 8) {
            float vx[8], vy[8], nn[8];
            #pragma unroll
            for (int u = 0; u < 8; ++u) {          // 8 independent 256B gathers
                int cc = __shfl(c, j + u);         // lanes >= m carry c=0,n=0
                ushort2 s = *reinterpret_cast<const ushort2*>(xlb + (size_t)cc * D + lane * 2);
                vx[u] = bf2f(s.x);
                vy[u] = bf2f(s.y);
                nn[u] = __shfl(n, j + u);
            }
            #pragma unroll
            for (int u = 0; u < 8; ++u) {
                ax = fmaf(nn[u], vx[u], ax);
                ay = fmaf(nn[u], vy[u], ay);
            }
        }
    }
    *reinterpret_cast<float2*>(out + (size_t)i * D + lane * 2) = make_float2(ax, ay);
}

// ======================= fallback (R1 atomic path) =======================
__global__ __launch_bounds__(256) void k_zero(int* __restrict__ p, int n) {
    int i = blockIdx.x * 256 + threadIdx.x;
    if (i < n) p[i] = 0;
}
__global__ __launch_bounds__(256) void k_deg(const int* __restrict__ cols,
                                             int* __restrict__ cntc, int E) {
    int e = blockIdx.x * 256 + threadIdx.x;
    if (e < E) atomicAdd(&cntc[cols[e]], 1);
}
#define GEMM_R 8
__global__ __launch_bounds__(128) void k_gemmf(const float* __restrict__ x,
                                               const float* __restrict__ W,
                                               const float* __restrict__ b,
                                               float* __restrict__ xl, int N) {
    __shared__ float xs[GEMM_R][D];
    const int c  = threadIdx.x;
    const int r0 = blockIdx.x * GEMM_R;
    #pragma unroll
    for (int r = 0; r < GEMM_R; ++r) {
        int row = r0 + r;
        xs[r][c] = (row < N) ? x[row * D + c] : 0.0f;
    }
    __syncthreads();
    float acc[GEMM_R];
    const float bc = b[c];
    #pragma unroll
    for (int r = 0; r < GEMM_R; ++r) acc[r] = bc;
    for (int k = 0; k < D; k += 4) {
        const float w0 = W[(k + 0) * D + c];
        const float w1 = W[(k + 1) * D + c];
        const float w2 = W[(k + 2) * D + c];
        const float w3 = W[(k + 3) * D + c];
        #pragma unroll
        for (int r = 0; r < GEMM_R; ++r) {
            const float4 xv = *reinterpret_cast<const float4*>(&xs[r][k]);
            acc[r] = fmaf(xv.x, w0, acc[r]);
            acc[r] = fmaf(xv.y, w1, acc[r]);
            acc[r] = fmaf(xv.z, w2, acc[r]);
            acc[r] = fmaf(xv.w, w3, acc[r]);
        }
    }
    #pragma unroll
    for (int r = 0; r < GEMM_R; ++r) {
        int row = r0 + r;
        if (row < N) xl[row * D + c] = acc[r];
    }
}
__global__ __launch_bounds__(256) void k_self(const float* __restrict__ xl,
                                              const float* __restrict__ dis,
                                              float* __restrict__ out, int N) {
    int gid = blockIdx.x * 256 + threadIdx.x;
    int i = gid >> 7;
    if (i < N) {
        float d = dis[i];
        out[gid] = d * d * xl[gid];
    }
}
__global__ __launch_bounds__(256) void k_scatter(const int* __restrict__ rows,
                                                 const int* __restrict__ cols,
                                                 const float* __restrict__ dis,
                                                 const float* __restrict__ xl,
                                                 float* __restrict__ out, int E) {
    long long gid = (long long)blockIdx.x * 256 + threadIdx.x;
    int e    = (int)(gid >> 6);
    int lane = (int)(gid & 63);
    if (e >= E) return;
    const int row = rows[e];
    const int col = cols[e];
    const float nrm = dis[row] * dis[col];
    atomicAdd(&out[row * D + lane],      nrm * xl[col * D + lane]);
    atomicAdd(&out[row * D + 64 + lane], nrm * xl[col * D + 64 + lane]);
}

// ======================= launch ==========================================
extern "C" void kernel_launch(void* const* d_in, const int* in_sizes, int n_in,
                              void* d_out, int out_size, void* d_ws, size_t ws_size,
                              hipStream_t stream) {
    const float* x   = (const float*)d_in[0];
    const int*   ei  = (const int*)d_in[1];
    const float* W   = (const float*)d_in[2];
    const float* b   = (const float*)d_in[3];
    float*       out = (float*)d_out;

    const int N = in_sizes[0] / D;   // 50000
    const int E = in_sizes[1] / 2;   // 1.6M
    const int* rows = ei;
    const int* cols = ei + E;
    const int NB = (N + RPB - 1) / RPB;        // 196
    const int NT = (E + TILE - 1) / TILE;      // 196
    const int CAP = (((2 * E) / NB) + 63) / 64 * 64;   // 2x mean bucket -> 16384

    // ws layout
    char* p = (char*)d_ws;
    size_t off = 0;
    unsigned short* xlb  = (unsigned short*)(p + off); off += (size_t)N * D * 2;
    unsigned short* wtb  = (unsigned short*)(p + off); off += (size_t)D * D * 2;
    float*          dis  = (float*)(p + off);          off += (size_t)N * 4;
    int*            cntc = (int*)(p + off);            off += (size_t)N * 4;
    int*            bcur = (int*)(p + off);            off += (size_t)MAXB * 4;
    int*            begN = (int*)(p + off);            off += (size_t)N * 4;
    int*            endN = (int*)(p + off);            off += (size_t)N * 4;
    unsigned*       ebuf = (unsigned*)(p + off);       off += (size_t)NB * CAP * 4;
    unsigned short* ecol = (unsigned short*)(p + off); off += (size_t)NB * CAP * 2;

    const int gN = (N + 255) / 256;
    const int gE = (E + 255) / 256;

    if (N <= 65536 && NB <= MAXB && CAP <= SPLIT_CAP && ws_size >= off) {
        k_init  <<<gN, 256, 0, stream>>>(cntc, bcur, N, NB, CAP);
        k_prepw <<<(D * D) / 256, 256, 0, stream>>>(W, wtb);
        k_bin   <<<NT, BINB, 0, stream>>>(rows, cols, bcur, ebuf, E, NB, CAP);
        k_deg2  <<<DTIL * DSEG, 1024, 0, stream>>>(cols, cntc, E, N);
        k_dis   <<<gN, 256, 0, stream>>>(cntc, dis, N);
        k_split <<<NB, 1024, 0, stream>>>(bcur, ebuf, ecol, begN, endN, N, CAP);
        k_gemm  <<<(N + 63) / 64, 256, 0, stream>>>(x, wtb, b, xlb, N);
        k_reduce<<<(N + 3) / 4, 256, 0, stream>>>(begN, endN, ecol, dis, xlb, out, N);
    } else {
        // fallback: R1 atomic scatter path (fp32 xl)
        char* q = (char*)d_ws;
        float* xl   = (float*)q;
        float* disF = (float*)(q + (size_t)N * D * 4);
        int*   cc   = (int*)(q + (size_t)N * D * 4 + (size_t)N * 4);
        k_zero <<<gN, 256, 0, stream>>>(cc, N);
        k_deg  <<<gE, 256, 0, stream>>>(cols, cc, E);
        k_dis  <<<gN, 256, 0, stream>>>(cc, disF, N);
        k_gemmf<<<(N + GEMM_R - 1) / GEMM_R, 128, 0, stream>>>(x, W, b, xl, N);
        k_self <<<((N * D) + 255) / 256, 256, 0, stream>>>(xl, disF, out, N);
        long long st = (long long)E * 64;
        k_scatter<<<(int)((st + 255) / 256), 256, 0, stream>>>(rows, cols, disF, xl, out, E);
    }
}